// Round 5
// baseline (3215.808 us; speedup 1.0000x reference)
//
#include <hip/hip_runtime.h>
#include <hip/hip_bf16.h>

typedef __attribute__((ext_vector_type(8))) short bf16x8;
typedef __attribute__((ext_vector_type(4))) float f32x4;

__device__ __forceinline__ void async16(const void* g, void* l) {
    __builtin_amdgcn_global_load_lds(
        (const __attribute__((address_space(1))) unsigned int*)g,
        (__attribute__((address_space(3))) unsigned int*)l, 16, 0, 0);
}

// ---------------------------------------------------------------------------
// pack_all: one node = pack_x (10240 blocks) + pack_a (640 blocks).
// pack_x: x5 f32 [16][512][16][300] -> X3 bf16 [16][16][300][512] channel-last.
// pack_a: weights -> A2f bf16 in MFMA-FRAGMENT order:
//   A2f block (g=row/16, kt): 1KB = lane l * 16B, lane l=(sq*16+fl) holds
//   row g*16+fl, k = kt*32 + sq*8 .. +8  (exactly the 16x16x32 A-operand frag)
// ---------------------------------------------------------------------------
__global__ __launch_bounds__(256) void pack_all(const float* __restrict__ x5,
                                                const float* __restrict__ conv_w,
                                                const float* __restrict__ cc_w,
                                                __hip_bfloat16* __restrict__ X3,
                                                __hip_bfloat16* __restrict__ A2f) {
    __shared__ __align__(16) float smem[64 * 65];
    const int f = blockIdx.x;
    if (f < 10240) {
        // ---- pack_x ----
        float(*tile)[65] = (float(*)[65])smem;
        const int ct = f / 1280, r = f % 1280;
        const int wt = r >> 8, bh = r & 255;
        const int b = bh >> 4, h = bh & 15;
        const int w0 = wt * 64, c0 = ct * 64;
        const int lw = (threadIdx.x & 15) * 4;
        const int lc = threadIdx.x >> 4;
#pragma unroll
        for (int i = 0; i < 4; ++i) {
            const int c = lc + i * 16;
            const int w = w0 + lw;
            const float* src = &x5[((size_t)(b * 512 + c0 + c) * 16 + h) * 300 + w];
            float4 v = {0.f, 0.f, 0.f, 0.f};
            if (w + 3 < 300) v = *(const float4*)src;
            else {
                if (w < 300)     v.x = src[0];
                if (w + 1 < 300) v.y = src[1];
                if (w + 2 < 300) v.z = src[2];
            }
            *(float4*)&tile[c][lw] = v;
        }
        __syncthreads();
        const int sc = (threadIdx.x & 15) * 4;
        const int sw0 = threadIdx.x >> 4;
#pragma unroll
        for (int i = 0; i < 4; ++i) {
            const int wl = sw0 + i * 16;
            const int w = w0 + wl;
            if (w < 300) {
                __hip_bfloat16 p[4];
                p[0] = __float2bfloat16(tile[sc + 0][wl]);
                p[1] = __float2bfloat16(tile[sc + 1][wl]);
                p[2] = __float2bfloat16(tile[sc + 2][wl]);
                p[3] = __float2bfloat16(tile[sc + 3][wl]);
                *(uint2*)&X3[(((size_t)(b * 16 + h) * 300 + w)) * 512 + c0 + sc] = *(uint2*)p;
            }
        }
    } else {
        // ---- pack_a ----
        float* w = smem;
        const int co = f - 10240;                 // 0..639
        if (co < 522) {
            const float4* src = (co < 512) ? (const float4*)(conv_w + (size_t)co * 3584)
                                           : (const float4*)(cc_w + (size_t)(co - 512) * 3584);
            for (int i = threadIdx.x; i < 896; i += 256) *(float4*)&w[i * 4] = src[i];
        } else {
            for (int i = threadIdx.x; i < 3584; i += 256) w[i] = 0.f;
        }
        __syncthreads();
        const int g = co >> 4, fl = co & 15;
        for (int chunk = threadIdx.x; chunk < 448; chunk += 256) {
            const int kk0 = chunk * 8;
            const int kt = kk0 >> 5, sq = (kk0 >> 3) & 3;
            __hip_bfloat16 p[8];
#pragma unroll
            for (int j = 0; j < 8; ++j) {
                const int k = kk0 + j;
                p[j] = __float2bfloat16(w[(k & 511) * 7 + (k >> 9)]);
            }
            char* dst = (char*)A2f + (((size_t)g * 112 + kt) * 64 + sq * 16 + fl) * 16;
            *(uint4*)dst = *(uint4*)p;
        }
    }
}

// ---------------------------------------------------------------------------
// conv_gemm: implicit-im2col MFMA GEMM.
//  - B (X3) staged via global_load_lds, XOR-swizzled, LDS double-buffered.
//  - A fragments loaded straight from L2-resident A2f (fragment-order,
//    coalesced dwordx4), register double-buffered -> LDS traffic halved.
//  - XCD-aware remap: all 35x reuse of X3 inside one XCD's L2.
// feats written channel-last [b][n][co] bf16; rows 512..521 -> scores f32.
// ---------------------------------------------------------------------------
__global__ __launch_bounds__(256, 6) void conv_gemm(
    const __hip_bfloat16* __restrict__ A2f, const __hip_bfloat16* __restrict__ X3,
    const float* __restrict__ conv_b, const float* __restrict__ cc_b,
    __hip_bfloat16* __restrict__ feats, float* __restrict__ scores) {
    __shared__ __align__(16) char lds[16384];   // B only: ph0 [0,8K) ph1 [8K,16K)
    const int tid = threadIdx.x;
    const int wv = tid >> 6;
    const int lane = tid & 63;

    // XCD-aware remap (1920 blocks = 8 XCD * 48 (nt,b) * 5 m)
    const int gid = blockIdx.x;
    const int xcd = gid & 7;
    const int j = gid >> 3;
    const int nb = xcd * 48 + j / 5;
    const int m0 = (j % 5) * 128;
    const int b = nb / 24;
    const int nt = nb % 24;

    // ---- B staging (global -> LDS) ----
    const int row0 = wv * 16 + (lane >> 2);            // 0..63
    const int kseg = (lane & 3) ^ ((lane >> 3) & 3);   // XOR-swizzled source segment
    int n0 = nt * 128 + row0;      if (n0 > 2999) n0 = 2999;
    int n1 = nt * 128 + row0 + 64; if (n1 > 2999) n1 = 2999;
    const char* gB0 = (const char*)X3 + ((size_t)((b * 16 + n0 / 300) * 300 + n0 % 300)) * 1024 + (size_t)kseg * 16;
    const char* gB1 = (const char*)X3 + ((size_t)((b * 16 + n1 / 300) * 300 + n1 % 300)) * 1024 + (size_t)kseg * 16;
    char* lB = lds + wv * 1024 + lane * 16;            // +4096: rows 64..127

    // ---- fragment read offsets ----
    const int wm = (wv & 1) * 64;
    const int wn = (wv >> 1) * 64;
    const int fl = lane & 15;
    const int sq = lane >> 4;
    int boff[4];
#pragma unroll
    for (int i = 0; i < 4; ++i) {
        const int swz = (sq ^ ((fl >> 1) & 3)) * 16;
        boff[i] = (wn + i * 16 + fl) * 64 + swz;
    }
    // A fragment source (fragment-order A2f, coalesced)
    const char* Af = (const char*)A2f;
    const int gb = (m0 >> 4) + ((wv & 1) << 2);        // row-group base for this wave

    f32x4 acc[4][4] = {};
    bf16x8 aC[4], aN[4];

#define ISSUE_B(kt, ph)                                                                \
    {                                                                                  \
        const size_t badd = (size_t)((kt) >> 4) * 307200 + (size_t)((kt) & 15) * 64;   \
        async16(gB0 + badd, lB + (ph) * 8192);                                         \
        async16(gB1 + badd, lB + (ph) * 8192 + 4096);                                  \
    }
#define PRE_A(kt, arr)                                                                 \
    {                                                                                  \
        _Pragma("unroll")                                                              \
        for (int mi = 0; mi < 4; ++mi)                                                 \
            arr[mi] = *(const bf16x8*)(Af + (((size_t)(gb + mi) * 112 + (kt)) << 10) + (lane << 4)); \
    }
#define COMPUTE(ph, arr)                                                               \
    {                                                                                  \
        _Pragma("unroll")                                                              \
        for (int ni = 0; ni < 4; ++ni) {                                               \
            const bf16x8 bv = *(const bf16x8*)(lds + (ph) * 8192 + boff[ni]);          \
            _Pragma("unroll")                                                          \
            for (int mi = 0; mi < 4; ++mi)                                             \
                acc[mi][ni] = __builtin_amdgcn_mfma_f32_16x16x32_bf16(arr[mi], bv, acc[mi][ni], 0, 0, 0); \
        }                                                                              \
    }

    ISSUE_B(0, 0);
    PRE_A(0, aC);
    for (int kt = 0; kt < 112; kt += 2) {
        __syncthreads();                       // vmcnt(0) drain: B(kt) + aC landed
        ISSUE_B(kt + 1, 1);
        PRE_A(kt + 1, aN);
        COMPUTE(0, aC);
        __syncthreads();                       // B(kt+1) + aN landed; buf0 reads done
        if (kt < 110) { ISSUE_B(kt + 2, 0); PRE_A(kt + 2, aC); }
        COMPUTE(1, aN);
    }
#undef ISSUE_B
#undef PRE_A
#undef COMPUTE

    const int quad4 = (lane >> 4) * 4;
#pragma unroll
    for (int ni = 0; ni < 4; ++ni) {
        const int n = nt * 128 + wn + ni * 16 + fl;
        if (n >= 3000) continue;
#pragma unroll
        for (int mi = 0; mi < 4; ++mi) {
            const int cob = m0 + wm + mi * 16 + quad4;
            const f32x4 v = acc[mi][ni];
            if (cob < 512) {
                __hip_bfloat16 p[4];
#pragma unroll
                for (int r = 0; r < 4; ++r)
                    p[r] = __float2bfloat16(fmaxf(v[r] + conv_b[cob + r], 0.f));
                *(uint2*)&feats[((size_t)(b * 3000 + n)) * 512 + cob] = *(uint2*)p;
            } else {
#pragma unroll
                for (int r = 0; r < 4; ++r) {
                    const int co = cob + r;
                    if (co < 522)
                        scores[(size_t)(b * 10 + (co - 512)) * 3000 + n] = v[r] + cc_b[co - 512];
                }
            }
        }
    }
}

// ---------------------------------------------------------------------------
// softmax over k=10 (in-place scores->assign), per-block asum partials
// (non-atomic), and zero agg for the next kernel. grid (16 b, 12 chunks).
// ---------------------------------------------------------------------------
__global__ __launch_bounds__(256) void softmax_assign(float* __restrict__ scores,
                                                      float* __restrict__ asum_part,
                                                      float* __restrict__ agg) {
    const int b = blockIdx.x;
    const int chunk = blockIdx.y;
    // zero agg slice (81920 floats over 192 blocks)
    const int zbase = (b * 12 + chunk) * 512 + threadIdx.x;
    if (zbase < 81920) agg[zbase] = 0.f;
    if (zbase + 256 < 81920) agg[zbase + 256] = 0.f;

    const int hw = chunk * 256 + threadIdx.x;
    const bool valid = hw < 3000;
    float part[10];
    if (valid) {
        float s[10], mx = -1e30f;
#pragma unroll
        for (int k = 0; k < 10; ++k) { s[k] = scores[(size_t)(b * 10 + k) * 3000 + hw]; mx = fmaxf(mx, s[k]); }
        float sum = 0.f;
#pragma unroll
        for (int k = 0; k < 10; ++k) { part[k] = __expf(s[k] - mx); sum += part[k]; }
        const float inv = 1.f / sum;
#pragma unroll
        for (int k = 0; k < 10; ++k) {
            part[k] *= inv;
            scores[(size_t)(b * 10 + k) * 3000 + hw] = part[k];
        }
    } else {
#pragma unroll
        for (int k = 0; k < 10; ++k) part[k] = 0.f;
    }
    __shared__ float red[4][10];
    const int lane = threadIdx.x & 63, w = threadIdx.x >> 6;
#pragma unroll
    for (int k = 0; k < 10; ++k) {
        float v = part[k];
        for (int off = 32; off; off >>= 1) v += __shfl_xor(v, off, 64);
        if (lane == 0) red[w][k] = v;
    }
    __syncthreads();
    if (threadIdx.x < 10)
        asum_part[(chunk * 16 + b) * 10 + threadIdx.x] =
            red[0][threadIdx.x] + red[1][threadIdx.x] + red[2][threadIdx.x] + red[3][threadIdx.x];
}

// ---------------------------------------------------------------------------
// agg[b][k][c] += sum_hw assign[b][k][hw] * feats[b][hw][c]. grid (12,16).
// ---------------------------------------------------------------------------
__global__ __launch_bounds__(256) void agg_kernel(const __hip_bfloat16* __restrict__ feats,
                                                  const float* __restrict__ assign,
                                                  float* __restrict__ agg) {
    const int chunk = blockIdx.x, b = blockIdx.y;
    const int c = threadIdx.x * 2;
    float acc0[10], acc1[10];
#pragma unroll
    for (int k = 0; k < 10; ++k) { acc0[k] = 0.f; acc1[k] = 0.f; }
    const int hw0 = chunk * 250;
    for (int i = 0; i < 250; ++i) {
        const int hw = hw0 + i;
        const __hip_bfloat162 f2 = *(const __hip_bfloat162*)&feats[((size_t)(b * 3000 + hw)) * 512 + c];
        const float f0 = __bfloat162float(f2.x), f1 = __bfloat162float(f2.y);
#pragma unroll
        for (int k = 0; k < 10; ++k) {
            const float a = assign[(size_t)(b * 10 + k) * 3000 + hw];
            acc0[k] += a * f0;
            acc1[k] += a * f1;
        }
    }
#pragma unroll
    for (int k = 0; k < 10; ++k) {
        atomicAdd(&agg[(size_t)(b * 10 + k) * 512 + c], acc0[k]);
        atomicAdd(&agg[(size_t)(b * 10 + k) * 512 + c + 1], acc1[k]);
    }
}

// ---------------------------------------------------------------------------
// fc_fused: residual + L2-normalize (k<8) + fc + relu -> out[0:8192].
// grid (16 co-tiles, 16 b), block 256. Residuals live in LDS only.
// ---------------------------------------------------------------------------
__global__ __launch_bounds__(256) void fc_fused(const float* __restrict__ agg,
                                                const float* __restrict__ asum_part,
                                                const float* __restrict__ centroids,
                                                const float* __restrict__ fc_w,
                                                const float* __restrict__ fc_b,
                                                float* __restrict__ out) {
    __shared__ float res[4096];
    __shared__ float sasum[8];
    __shared__ float red[4][8];
    __shared__ float scale[8];
    const int b = blockIdx.y;
    const int t = threadIdx.x;
    if (t < 8) {
        float s = 0.f;
#pragma unroll
        for (int p = 0; p < 12; ++p) s += asum_part[(p * 16 + b) * 10 + t];
        sasum[t] = s;
    }
    __syncthreads();
    float sq[8];
#pragma unroll
    for (int k = 0; k < 8; ++k) sq[k] = 0.f;
#pragma unroll
    for (int jj = 0; jj < 16; ++jj) {
        const int i = t + jj * 256;
        const int k = jj >> 1;           // i>>9 == jj>>1 (t<256)
        const int c = i & 511;
        const float r = agg[(size_t)(b * 10 + k) * 512 + c] - sasum[k] * centroids[k * 512 + c];
        res[i] = r;
        sq[k] += r * r;
    }
    const int lane = t & 63, w = t >> 6;
#pragma unroll
    for (int k = 0; k < 8; ++k) {
        float v = sq[k];
        for (int off = 32; off; off >>= 1) v += __shfl_xor(v, off, 64);
        if (lane == 0) red[w][k] = v;
    }
    __syncthreads();
    if (t < 8) {
        const float nrm = sqrtf(red[0][t] + red[1][t] + red[2][t] + red[3][t]);
        scale[t] = 1.f / fmaxf(nrm, 1e-12f);
    }
    __syncthreads();

    const int col = t >> 3;
    const int ks = t & 7;
    const int co = blockIdx.x * 32 + col;
    const float4* w4 = (const float4*)(fc_w + (size_t)co * 4096);
    float acc = 0.f;
    for (int i = ks; i < 1024; i += 8) {
        const float4 wv = w4[i];
        const float4 rv = *(const float4*)&res[i * 4];
        acc += (rv.x * wv.x + rv.y * wv.y + rv.z * wv.z + rv.w * wv.w) * scale[i >> 7];
    }
    acc += __shfl_down(acc, 4, 8);
    acc += __shfl_down(acc, 2, 8);
    acc += __shfl_down(acc, 1, 8);
    if (ks == 0) out[b * 512 + co] = fmaxf(acc + fc_b[co], 0.f);
}

// ---------------------------------------------------------------------------
// logit: XCD-grouped. grid 384.
// ---------------------------------------------------------------------------
__global__ __launch_bounds__(256) void logit_kernel(const float* __restrict__ emb,
                                                    const float* __restrict__ logit_w,
                                                    float* __restrict__ out) {
    __shared__ float se[512];
    const int gid = blockIdx.x;
    const int xcd = gid & 7;
    const int j = gid >> 3;
    const int otile = xcd * 3 + (j >> 4);
    const int b = j & 15;
    se[threadIdx.x] = emb[b * 512 + threadIdx.x];
    se[threadIdx.x + 256] = emb[b * 512 + threadIdx.x + 256];
    __syncthreads();
    const int o = otile * 256 + threadIdx.x;
    if (o < 5994) {
        const float4* w4 = (const float4*)(logit_w + (size_t)o * 512);
        float acc = 0.f;
        for (int i = 0; i < 128; ++i) {
            const float4 w = w4[i];
            acc += w.x * se[4 * i] + w.y * se[4 * i + 1] + w.z * se[4 * i + 2] + w.w * se[4 * i + 3];
        }
        out[8192 + b * 5994 + o] = acc;
    }
}

extern "C" void kernel_launch(void* const* d_in, const int* in_sizes, int n_in,
                              void* d_out, int out_size, void* d_ws, size_t ws_size,
                              hipStream_t stream) {
    (void)in_sizes; (void)n_in; (void)out_size; (void)ws_size;
    const float* x5       = (const float*)d_in[0];
    const float* conv_w   = (const float*)d_in[5];
    const float* conv_b   = (const float*)d_in[6];
    const float* cc_w     = (const float*)d_in[7];
    const float* cc_b     = (const float*)d_in[8];
    const float* centroids= (const float*)d_in[9];
    const float* fc_w     = (const float*)d_in[10];
    const float* fc_b     = (const float*)d_in[11];
    const float* logit_w  = (const float*)d_in[12];
    float* out = (float*)d_out;

    char* ws = (char*)d_ws;
    __hip_bfloat16* X3    = (__hip_bfloat16*)(ws);              // 78,643,200 B
    __hip_bfloat16* A2f   = (__hip_bfloat16*)(ws + 78643200);   //  4,587,520 B (fragment-order)
    __hip_bfloat16* feats = (__hip_bfloat16*)(ws + 83230720);   // 49,152,000 B (channel-last)
    float* scores         = (float*)(ws + 132382720);           //  1,920,000 B
    float* asum_part      = (float*)(ws + 134302720);           //      7,680 B
    float* agg            = (float*)(ws + 134310400);           //    327,680 B

    pack_all<<<dim3(10880), 256, 0, stream>>>(x5, conv_w, cc_w, X3, A2f);
    conv_gemm<<<dim3(1920), 256, 0, stream>>>(A2f, X3, conv_b, cc_b, feats, scores);
    softmax_assign<<<dim3(16, 12), 256, 0, stream>>>(scores, asum_part, agg);
    agg_kernel<<<dim3(12, 16), 256, 0, stream>>>(feats, scores, agg);
    fc_fused<<<dim3(16, 16), 256, 0, stream>>>(agg, asum_part, centroids, fc_w, fc_b, out);
    logit_kernel<<<dim3(384), 256, 0, stream>>>(out, logit_w, out);
}

// Round 6
// 664.111 us; speedup vs baseline: 4.8423x; 4.8423x over previous
//
#include <hip/hip_runtime.h>
#include <hip/hip_bf16.h>

typedef __attribute__((ext_vector_type(8))) short bf16x8;
typedef __attribute__((ext_vector_type(4))) float f32x4;

__device__ __forceinline__ void async16(const void* g, void* l) {
    __builtin_amdgcn_global_load_lds(
        (const __attribute__((address_space(1))) unsigned int*)g,
        (__attribute__((address_space(3))) unsigned int*)l, 16, 0, 0);
}

// ---------------------------------------------------------------------------
// pack_all: one node = pack_x (10240 blocks) + pack_a (640 blocks).
// pack_x: x5 f32 [16][512][16][300] -> X3 bf16 [16][16][300][512] channel-last.
// pack_a: weights -> A2f bf16 in MFMA-FRAGMENT order:
//   A2f block (g=row/16, kt): 1KB = lane l * 16B, lane l=(sq*16+fl) holds
//   row g*16+fl, k = kt*32 + sq*8 .. +8  (exactly the 16x16x32 A-operand frag)
// ---------------------------------------------------------------------------
__global__ __launch_bounds__(256) void pack_all(const float* __restrict__ x5,
                                                const float* __restrict__ conv_w,
                                                const float* __restrict__ cc_w,
                                                __hip_bfloat16* __restrict__ X3,
                                                __hip_bfloat16* __restrict__ A2f) {
    __shared__ __align__(16) float smem[64 * 65];
    const int f = blockIdx.x;
    if (f < 10240) {
        // ---- pack_x ----
        float(*tile)[65] = (float(*)[65])smem;
        const int ct = f / 1280, r = f % 1280;
        const int wt = r >> 8, bh = r & 255;
        const int b = bh >> 4, h = bh & 15;
        const int w0 = wt * 64, c0 = ct * 64;
        const int lw = (threadIdx.x & 15) * 4;
        const int lc = threadIdx.x >> 4;
#pragma unroll
        for (int i = 0; i < 4; ++i) {
            const int c = lc + i * 16;
            const int w = w0 + lw;
            const float* src = &x5[((size_t)(b * 512 + c0 + c) * 16 + h) * 300 + w];
            float4 v = {0.f, 0.f, 0.f, 0.f};
            if (w + 3 < 300) v = *(const float4*)src;
            else {
                if (w < 300)     v.x = src[0];
                if (w + 1 < 300) v.y = src[1];
                if (w + 2 < 300) v.z = src[2];
            }
            *(float4*)&tile[c][lw] = v;
        }
        __syncthreads();
        const int sc = (threadIdx.x & 15) * 4;
        const int sw0 = threadIdx.x >> 4;
#pragma unroll
        for (int i = 0; i < 4; ++i) {
            const int wl = sw0 + i * 16;
            const int w = w0 + wl;
            if (w < 300) {
                __hip_bfloat16 p[4];
                p[0] = __float2bfloat16(tile[sc + 0][wl]);
                p[1] = __float2bfloat16(tile[sc + 1][wl]);
                p[2] = __float2bfloat16(tile[sc + 2][wl]);
                p[3] = __float2bfloat16(tile[sc + 3][wl]);
                *(uint2*)&X3[(((size_t)(b * 16 + h) * 300 + w)) * 512 + c0 + sc] = *(uint2*)p;
            }
        }
    } else {
        // ---- pack_a ----
        float* w = smem;
        const int co = f - 10240;                 // 0..639
        if (co < 522) {
            const float4* src = (co < 512) ? (const float4*)(conv_w + (size_t)co * 3584)
                                           : (const float4*)(cc_w + (size_t)(co - 512) * 3584);
            for (int i = threadIdx.x; i < 896; i += 256) *(float4*)&w[i * 4] = src[i];
        } else {
            for (int i = threadIdx.x; i < 3584; i += 256) w[i] = 0.f;
        }
        __syncthreads();
        const int g = co >> 4, fl = co & 15;
        for (int chunk = threadIdx.x; chunk < 448; chunk += 256) {
            const int kk0 = chunk * 8;
            const int kt = kk0 >> 5, sq = (kk0 >> 3) & 3;
            __hip_bfloat16 p[8];
#pragma unroll
            for (int j = 0; j < 8; ++j) {
                const int k = kk0 + j;
                p[j] = __float2bfloat16(w[(k & 511) * 7 + (k >> 9)]);
            }
            char* dst = (char*)A2f + (((size_t)g * 112 + kt) * 64 + sq * 16 + fl) * 16;
            *(uint4*)dst = *(uint4*)p;
        }
    }
}

// ---------------------------------------------------------------------------
// conv_gemm: implicit-im2col MFMA GEMM.
//  - B (X3) staged via global_load_lds, XOR-swizzled, LDS double-buffered.
//  - A fragments loaded straight from L2-resident A2f (fragment-order,
//    coalesced dwordx4), register double-buffered -> LDS traffic halved.
//  - XCD-aware remap: all 35x reuse of X3 inside one XCD's L2.
//  - __launch_bounds__(256,4): 128-reg budget fits ~115 live regs.
//    (256,6) in R5 forced an ~85-reg budget -> accumulator spill -> 7.5 GB
//    scratch writes, MfmaUtil 3%. Do NOT raise the min-waves bound here.
// feats written channel-last [b][n][co] bf16; rows 512..521 -> scores f32.
// ---------------------------------------------------------------------------
__global__ __launch_bounds__(256, 4) void conv_gemm(
    const __hip_bfloat16* __restrict__ A2f, const __hip_bfloat16* __restrict__ X3,
    const float* __restrict__ conv_b, const float* __restrict__ cc_b,
    __hip_bfloat16* __restrict__ feats, float* __restrict__ scores) {
    __shared__ __align__(16) char lds[16384];   // B only: ph0 [0,8K) ph1 [8K,16K)
    const int tid = threadIdx.x;
    const int wv = tid >> 6;
    const int lane = tid & 63;

    // XCD-aware remap (1920 blocks = 8 XCD * 48 (nt,b) * 5 m)
    const int gid = blockIdx.x;
    const int xcd = gid & 7;
    const int j = gid >> 3;
    const int nb = xcd * 48 + j / 5;
    const int m0 = (j % 5) * 128;
    const int b = nb / 24;
    const int nt = nb % 24;

    // ---- B staging (global -> LDS) ----
    const int row0 = wv * 16 + (lane >> 2);            // 0..63
    const int kseg = (lane & 3) ^ ((lane >> 3) & 3);   // XOR-swizzled source segment
    int n0 = nt * 128 + row0;      if (n0 > 2999) n0 = 2999;
    int n1 = nt * 128 + row0 + 64; if (n1 > 2999) n1 = 2999;
    const char* gB0 = (const char*)X3 + ((size_t)((b * 16 + n0 / 300) * 300 + n0 % 300)) * 1024 + (size_t)kseg * 16;
    const char* gB1 = (const char*)X3 + ((size_t)((b * 16 + n1 / 300) * 300 + n1 % 300)) * 1024 + (size_t)kseg * 16;
    char* lB = lds + wv * 1024 + lane * 16;            // +4096: rows 64..127

    // ---- fragment read offsets ----
    const int wm = (wv & 1) * 64;
    const int wn = (wv >> 1) * 64;
    const int fl = lane & 15;
    const int sq = lane >> 4;
    int boff[4];
#pragma unroll
    for (int i = 0; i < 4; ++i) {
        const int swz = (sq ^ ((fl >> 1) & 3)) * 16;
        boff[i] = (wn + i * 16 + fl) * 64 + swz;
    }
    // A fragment source (fragment-order A2f, coalesced)
    const char* Af = (const char*)A2f;
    const int gb = (m0 >> 4) + ((wv & 1) << 2);        // row-group base for this wave

    f32x4 acc[4][4] = {};
    bf16x8 aC[4], aN[4];

#define ISSUE_B(kt, ph)                                                                \
    {                                                                                  \
        const size_t badd = (size_t)((kt) >> 4) * 307200 + (size_t)((kt) & 15) * 64;   \
        async16(gB0 + badd, lB + (ph) * 8192);                                         \
        async16(gB1 + badd, lB + (ph) * 8192 + 4096);                                  \
    }
#define PRE_A(kt, arr)                                                                 \
    {                                                                                  \
        _Pragma("unroll")                                                              \
        for (int mi = 0; mi < 4; ++mi)                                                 \
            arr[mi] = *(const bf16x8*)(Af + (((size_t)(gb + mi) * 112 + (kt)) << 10) + (lane << 4)); \
    }
#define COMPUTE(ph, arr)                                                               \
    {                                                                                  \
        _Pragma("unroll")                                                              \
        for (int ni = 0; ni < 4; ++ni) {                                               \
            const bf16x8 bv = *(const bf16x8*)(lds + (ph) * 8192 + boff[ni]);          \
            _Pragma("unroll")                                                          \
            for (int mi = 0; mi < 4; ++mi)                                             \
                acc[mi][ni] = __builtin_amdgcn_mfma_f32_16x16x32_bf16(arr[mi], bv, acc[mi][ni], 0, 0, 0); \
        }                                                                              \
    }

    ISSUE_B(0, 0);
    PRE_A(0, aC);
    for (int kt = 0; kt < 112; kt += 2) {
        __syncthreads();                       // vmcnt(0) drain: B(kt) + aC landed
        ISSUE_B(kt + 1, 1);
        PRE_A(kt + 1, aN);
        COMPUTE(0, aC);
        __syncthreads();                       // B(kt+1) + aN landed; buf0 reads done
        if (kt < 110) { ISSUE_B(kt + 2, 0); PRE_A(kt + 2, aC); }
        COMPUTE(1, aN);
    }
#undef ISSUE_B
#undef PRE_A
#undef COMPUTE

    const int quad4 = (lane >> 4) * 4;
#pragma unroll
    for (int ni = 0; ni < 4; ++ni) {
        const int n = nt * 128 + wn + ni * 16 + fl;
        if (n >= 3000) continue;
#pragma unroll
        for (int mi = 0; mi < 4; ++mi) {
            const int cob = m0 + wm + mi * 16 + quad4;
            const f32x4 v = acc[mi][ni];
            if (cob < 512) {
                __hip_bfloat16 p[4];
#pragma unroll
                for (int r = 0; r < 4; ++r)
                    p[r] = __float2bfloat16(fmaxf(v[r] + conv_b[cob + r], 0.f));
                *(uint2*)&feats[((size_t)(b * 3000 + n)) * 512 + cob] = *(uint2*)p;
            } else {
#pragma unroll
                for (int r = 0; r < 4; ++r) {
                    const int co = cob + r;
                    if (co < 522)
                        scores[(size_t)(b * 10 + (co - 512)) * 3000 + n] = v[r] + cc_b[co - 512];
                }
            }
        }
    }
}

// ---------------------------------------------------------------------------
// softmax over k=10 (in-place scores->assign), per-block asum partials
// (non-atomic), and zero agg for the next kernel. grid (16 b, 12 chunks).
// ---------------------------------------------------------------------------
__global__ __launch_bounds__(256) void softmax_assign(float* __restrict__ scores,
                                                      float* __restrict__ asum_part,
                                                      float* __restrict__ agg) {
    const int b = blockIdx.x;
    const int chunk = blockIdx.y;
    const int zbase = (b * 12 + chunk) * 512 + threadIdx.x;
    if (zbase < 81920) agg[zbase] = 0.f;
    if (zbase + 256 < 81920) agg[zbase + 256] = 0.f;

    const int hw = chunk * 256 + threadIdx.x;
    const bool valid = hw < 3000;
    float part[10];
    if (valid) {
        float s[10], mx = -1e30f;
#pragma unroll
        for (int k = 0; k < 10; ++k) { s[k] = scores[(size_t)(b * 10 + k) * 3000 + hw]; mx = fmaxf(mx, s[k]); }
        float sum = 0.f;
#pragma unroll
        for (int k = 0; k < 10; ++k) { part[k] = __expf(s[k] - mx); sum += part[k]; }
        const float inv = 1.f / sum;
#pragma unroll
        for (int k = 0; k < 10; ++k) {
            part[k] *= inv;
            scores[(size_t)(b * 10 + k) * 3000 + hw] = part[k];
        }
    } else {
#pragma unroll
        for (int k = 0; k < 10; ++k) part[k] = 0.f;
    }
    __shared__ float red[4][10];
    const int lane = threadIdx.x & 63, w = threadIdx.x >> 6;
#pragma unroll
    for (int k = 0; k < 10; ++k) {
        float v = part[k];
        for (int off = 32; off; off >>= 1) v += __shfl_xor(v, off, 64);
        if (lane == 0) red[w][k] = v;
    }
    __syncthreads();
    if (threadIdx.x < 10)
        asum_part[(chunk * 16 + b) * 10 + threadIdx.x] =
            red[0][threadIdx.x] + red[1][threadIdx.x] + red[2][threadIdx.x] + red[3][threadIdx.x];
}

// ---------------------------------------------------------------------------
// agg[b][k][c] += sum_hw assign[b][k][hw] * feats[b][hw][c]. grid (12,16).
// ---------------------------------------------------------------------------
__global__ __launch_bounds__(256) void agg_kernel(const __hip_bfloat16* __restrict__ feats,
                                                  const float* __restrict__ assign,
                                                  float* __restrict__ agg) {
    const int chunk = blockIdx.x, b = blockIdx.y;
    const int c = threadIdx.x * 2;
    float acc0[10], acc1[10];
#pragma unroll
    for (int k = 0; k < 10; ++k) { acc0[k] = 0.f; acc1[k] = 0.f; }
    const int hw0 = chunk * 250;
    for (int i = 0; i < 250; ++i) {
        const int hw = hw0 + i;
        const __hip_bfloat162 f2 = *(const __hip_bfloat162*)&feats[((size_t)(b * 3000 + hw)) * 512 + c];
        const float f0 = __bfloat162float(f2.x), f1 = __bfloat162float(f2.y);
#pragma unroll
        for (int k = 0; k < 10; ++k) {
            const float a = assign[(size_t)(b * 10 + k) * 3000 + hw];
            acc0[k] += a * f0;
            acc1[k] += a * f1;
        }
    }
#pragma unroll
    for (int k = 0; k < 10; ++k) {
        atomicAdd(&agg[(size_t)(b * 10 + k) * 512 + c], acc0[k]);
        atomicAdd(&agg[(size_t)(b * 10 + k) * 512 + c + 1], acc1[k]);
    }
}

// ---------------------------------------------------------------------------
// fc_fused: residual + L2-normalize (k<8) + fc + relu -> out[0:8192].
// grid (16 co-tiles, 16 b), block 256. Residuals live in LDS only.
// ---------------------------------------------------------------------------
__global__ __launch_bounds__(256) void fc_fused(const float* __restrict__ agg,
                                                const float* __restrict__ asum_part,
                                                const float* __restrict__ centroids,
                                                const float* __restrict__ fc_w,
                                                const float* __restrict__ fc_b,
                                                float* __restrict__ out) {
    __shared__ float res[4096];
    __shared__ float sasum[8];
    __shared__ float red[4][8];
    __shared__ float scale[8];
    const int b = blockIdx.y;
    const int t = threadIdx.x;
    if (t < 8) {
        float s = 0.f;
#pragma unroll
        for (int p = 0; p < 12; ++p) s += asum_part[(p * 16 + b) * 10 + t];
        sasum[t] = s;
    }
    __syncthreads();
    float sq[8];
#pragma unroll
    for (int k = 0; k < 8; ++k) sq[k] = 0.f;
#pragma unroll
    for (int jj = 0; jj < 16; ++jj) {
        const int i = t + jj * 256;
        const int k = jj >> 1;
        const int c = i & 511;
        const float r = agg[(size_t)(b * 10 + k) * 512 + c] - sasum[k] * centroids[k * 512 + c];
        res[i] = r;
        sq[k] += r * r;
    }
    const int lane = t & 63, w = t >> 6;
#pragma unroll
    for (int k = 0; k < 8; ++k) {
        float v = sq[k];
        for (int off = 32; off; off >>= 1) v += __shfl_xor(v, off, 64);
        if (lane == 0) red[w][k] = v;
    }
    __syncthreads();
    if (t < 8) {
        const float nrm = sqrtf(red[0][t] + red[1][t] + red[2][t] + red[3][t]);
        scale[t] = 1.f / fmaxf(nrm, 1e-12f);
    }
    __syncthreads();

    const int col = t >> 3;
    const int ks = t & 7;
    const int co = blockIdx.x * 32 + col;
    const float4* w4 = (const float4*)(fc_w + (size_t)co * 4096);
    float acc = 0.f;
    for (int i = ks; i < 1024; i += 8) {
        const float4 wv = w4[i];
        const float4 rv = *(const float4*)&res[i * 4];
        acc += (rv.x * wv.x + rv.y * wv.y + rv.z * wv.z + rv.w * wv.w) * scale[i >> 7];
    }
    acc += __shfl_down(acc, 4, 8);
    acc += __shfl_down(acc, 2, 8);
    acc += __shfl_down(acc, 1, 8);
    if (ks == 0) out[b * 512 + co] = fmaxf(acc + fc_b[co], 0.f);
}

// ---------------------------------------------------------------------------
// logit: XCD-grouped. grid 384.
// ---------------------------------------------------------------------------
__global__ __launch_bounds__(256) void logit_kernel(const float* __restrict__ emb,
                                                    const float* __restrict__ logit_w,
                                                    float* __restrict__ out) {
    __shared__ float se[512];
    const int gid = blockIdx.x;
    const int xcd = gid & 7;
    const int j = gid >> 3;
    const int otile = xcd * 3 + (j >> 4);
    const int b = j & 15;
    se[threadIdx.x] = emb[b * 512 + threadIdx.x];
    se[threadIdx.x + 256] = emb[b * 512 + threadIdx.x + 256];
    __syncthreads();
    const int o = otile * 256 + threadIdx.x;
    if (o < 5994) {
        const float4* w4 = (const float4*)(logit_w + (size_t)o * 512);
        float acc = 0.f;
        for (int i = 0; i < 128; ++i) {
            const float4 w = w4[i];
            acc += w.x * se[4 * i] + w.y * se[4 * i + 1] + w.z * se[4 * i + 2] + w.w * se[4 * i + 3];
        }
        out[8192 + b * 5994 + o] = acc;
    }
}

extern "C" void kernel_launch(void* const* d_in, const int* in_sizes, int n_in,
                              void* d_out, int out_size, void* d_ws, size_t ws_size,
                              hipStream_t stream) {
    (void)in_sizes; (void)n_in; (void)out_size; (void)ws_size;
    const float* x5       = (const float*)d_in[0];
    const float* conv_w   = (const float*)d_in[5];
    const float* conv_b   = (const float*)d_in[6];
    const float* cc_w     = (const float*)d_in[7];
    const float* cc_b     = (const float*)d_in[8];
    const float* centroids= (const float*)d_in[9];
    const float* fc_w     = (const float*)d_in[10];
    const float* fc_b     = (const float*)d_in[11];
    const float* logit_w  = (const float*)d_in[12];
    float* out = (float*)d_out;

    char* ws = (char*)d_ws;
    __hip_bfloat16* X3    = (__hip_bfloat16*)(ws);              // 78,643,200 B
    __hip_bfloat16* A2f   = (__hip_bfloat16*)(ws + 78643200);   //  4,587,520 B (fragment-order)
    __hip_bfloat16* feats = (__hip_bfloat16*)(ws + 83230720);   // 49,152,000 B (channel-last)
    float* scores         = (float*)(ws + 132382720);           //  1,920,000 B
    float* asum_part      = (float*)(ws + 134302720);           //      7,680 B
    float* agg            = (float*)(ws + 134310400);           //    327,680 B

    pack_all<<<dim3(10880), 256, 0, stream>>>(x5, conv_w, cc_w, X3, A2f);
    conv_gemm<<<dim3(1920), 256, 0, stream>>>(A2f, X3, conv_b, cc_b, feats, scores);
    softmax_assign<<<dim3(16, 12), 256, 0, stream>>>(scores, asum_part, agg);
    agg_kernel<<<dim3(12, 16), 256, 0, stream>>>(feats, scores, agg);
    fc_fused<<<dim3(16, 16), 256, 0, stream>>>(agg, asum_part, centroids, fc_w, fc_b, out);
    logit_kernel<<<dim3(384), 256, 0, stream>>>(out, logit_w, out);
}